// Round 19
// baseline (389.579 us; speedup 1.0000x reference)
//
#include <hip/hip_runtime.h>
#include <stdint.h>

typedef __attribute__((ext_vector_type(8))) short short8;
typedef __attribute__((ext_vector_type(4))) float float4v;

#define SEQ 4096
#define HD 64
#define QB 128
#define KT 64
#define HEADS 16
#define NT (SEQ / KT)
#define NTH (NT / 2)            // tiles per wave-half in pass 1
#define MWORDS (SEQ / 64)       // uint64 mask words per row
#define TILE_BYTES 8192         // 64x64 bf16, fragment-order layout
#define QSCALE 0.18033688f      // 0.125 * log2(e)  (temperature + exp2 folding)

__device__ __forceinline__ ushort f2bf(float f) {
    union { float f; uint32_t u; } x; x.f = f;
    uint32_t u = x.u;
    return (ushort)((u + 0x7FFFu + ((u >> 16) & 1u)) >> 16);  // RNE
}

__device__ __forceinline__ uint32_t cvt_pk_bf16(float lo, float hi) {
    uint32_t r;
    asm("v_cvt_pk_bf16_f32 %0, %1, %2" : "=v"(r) : "v"(lo), "v"(hi));
    return r;
}

__device__ __forceinline__ float exp2_hw(float x) { return __builtin_amdgcn_exp2f(x); }
__device__ __forceinline__ float log2_hw(float x) { return __builtin_amdgcn_logf(x); }

__device__ __forceinline__ void gload_lds16(const void* g, void* l) {
    __builtin_amdgcn_global_load_lds(
        (const __attribute__((address_space(1))) uint32_t*)g,
        (__attribute__((address_space(3))) uint32_t*)l, 16, 0, 0);
}

// ---------------- mask bit-pack: [4096][4096] int32 -> [4096][64] uint64 ----------------
__global__ __launch_bounds__(256) void pack_mask_kernel(const int* __restrict__ mask,
                                                        unsigned long long* __restrict__ mb) {
    const int qrow = blockIdx.x;
    const int wave = threadIdx.x >> 6;
    const int lane = threadIdx.x & 63;
    const int* rp = mask + (size_t)qrow * SEQ;
    #pragma unroll
    for (int i = 0; i < 16; ++i) {
        const int widx = wave * 16 + i;
        const int mv = rp[widx * 64 + lane];
        unsigned long long b = __ballot(mv != 0);
        if (lane == 0) mb[(size_t)qrow * MWORDS + widx] = b;
    }
}

// ---------------- K/V -> bf16 tiles in MFMA fragment order ----------------
__global__ __launch_bounds__(256) void prep_kv_kernel(const float* __restrict__ kg,
                                                      const float* __restrict__ vg,
                                                      char* __restrict__ ktiles,
                                                      char* __restrict__ vtiles) {
    __shared__ __align__(16) float Tl[64][68];
    const int bid = blockIdx.x;               // head*64 + kt
    const int tid = threadIdx.x;
    const float* Kg = kg + (size_t)bid * KT * HD;
    const float* Vg = vg + (size_t)bid * KT * HD;
    char* Kt = ktiles + (size_t)bid * TILE_BYTES;
    char* Vt = vtiles + (size_t)bid * TILE_BYTES;

    {   // stage K coalesced
        const int r = tid >> 2, c0 = (tid & 3) * 16;
        #pragma unroll
        for (int j = 0; j < 4; ++j)
            *(float4v*)&Tl[r][c0 + j * 4] = *(const float4v*)(Kg + r * HD + c0 + j * 4);
    }
    __syncthreads();
    #pragma unroll
    for (int cc = 0; cc < 2; ++cc) {
        const int c = tid + cc * 256;
        const int t = c >> 7, h = (c >> 6) & 1, g = (c >> 4) & 3, li = c & 15;
        const int row = 32 * (t >> 1) + 8 * (li >> 2) + 4 * (t & 1) + (li & 3);
        const float* src = &Tl[row][h * 32 + g * 8];
        short8 w;
        #pragma unroll
        for (int e = 0; e < 8; ++e) w[e] = (short)f2bf(src[e]);
        *(short8*)(Kt + c * 16) = w;
    }
    __syncthreads();
    {   // stage V coalesced
        const int r = tid >> 2, c0 = (tid & 3) * 16;
        #pragma unroll
        for (int j = 0; j < 4; ++j)
            *(float4v*)&Tl[r][c0 + j * 4] = *(const float4v*)(Vg + r * HD + c0 + j * 4);
    }
    __syncthreads();
    #pragma unroll
    for (int cc = 0; cc < 2; ++cc) {
        const int c = tid + cc * 256;
        const int dt = c >> 7, h = (c >> 6) & 1, g = (c >> 4) & 3, li = c & 15;
        short8 w;
        #pragma unroll
        for (int e = 0; e < 8; ++e) w[e] = (short)f2bf(Tl[h * 32 + g * 8 + e][dt * 16 + li]);
        *(short8*)(Vt + c * 16) = w;
    }
}

// pass-2 staging: EVEN waves only (ew = wave>>1 in 0..3), 2KB per even wave
#define STAGE2_K(KTI) do {                                                              \
    const char* _s = Ktile + (size_t)(KTI) * TILE_BYTES + ew * 2048 + lane * 16;        \
    char* _d = (char*)LdsK[(KTI) & 3] + ew * 2048;                                      \
    gload_lds16(_s, _d); gload_lds16(_s + 1024, _d + 1024);                             \
} while (0)

#define STAGE2_V(KTI) do {                                                              \
    const char* _s = Vtile + (size_t)(KTI) * TILE_BYTES + ew * 2048 + lane * 16;        \
    char* _d = (char*)LdsV[(KTI) & 3] + ew * 2048;                                      \
} while (0)
#undef STAGE2_V
#define STAGE2_V(KTI) do {                                                              \
    const char* _s = Vtile + (size_t)(KTI) * TILE_BYTES + ew * 2048 + lane * 16;        \
    char* _d = (char*)LdsV[(KTI) & 3] + ew * 2048;                                      \
    gload_lds16(_s, _d); gload_lds16(_s + 1024, _d + 1024);                             \
} while (0)

// pass-1 staging: 4 waves per half, each stages 2KB of its half's tile
#define STAGE_P1(TI, DST) do {                                                          \
    const char* _s = Ktile + (size_t)(kt0 + (TI)) * TILE_BYTES + w4 * 2048 + lane * 16; \
    char* _d = (char*)(DST) + w4 * 2048;                                                \
    gload_lds16(_s, _d); gload_lds16(_s + 1024, _d + 1024);                             \
} while (0)

// ---------------- fused attention: 8 waves, QB=128 ----------------
// Pass 1: wave-pair tile-split — waves 0-3 own tiles 0..31, waves 4-7 own 32..63;
//   each wave covers 2 q-sets (32 rows), so bk LDS reads serve 2x the rows (pass-1
//   LDS traffic and iteration count both halve). Partial lsums merge via LDS.
// Pass 2: R18's phase-staggered QK/FIN slots (even waves one slot ahead).
__global__ __launch_bounds__(512, 4) void attn_kernel(
    const float* __restrict__ qg, const unsigned long long* __restrict__ mb,
    const char* __restrict__ ktiles, const char* __restrict__ vtiles,
    float* __restrict__ outg, float* __restrict__ attng)
{
    __shared__ __align__(16) char LdsK[4][TILE_BYTES];
    __shared__ __align__(16) char LdsV[4][TILE_BYTES];

    const int tid  = threadIdx.x;
    const int wave = tid >> 6;    // 0..7
    const int lane = tid & 63;
    const int g    = lane >> 4;
    const int li   = lane & 15;

    // XCD-aware swizzle: 64 blocks (2 heads) per XCD -> K/V tiles L2-resident
    const int bid = blockIdx.x;               // 0..511
    const int blk = (bid & 7) * 64 + (bid >> 3);
    const int bh  = blk >> 5;
    const int qb  = blk & 31;

    const size_t qkvBase = (size_t)bh * SEQ * HD;
    const float* Qg = qg + qkvBase + (size_t)qb * QB * HD;
    const char* Ktile = ktiles + (size_t)bh * NT * TILE_BYTES;
    const char* Vtile = vtiles + (size_t)bh * NT * TILE_BYTES;

    // ---- pass-2 Q B-fragments (0.125 * log2e folded) ----
    const int wq0 = wave * 16;
    short8 aq[2];
    #pragma unroll
    for (int h = 0; h < 2; ++h) {
        const float* src = Qg + (wq0 + li) * HD + h * 32 + g * 8;
        short8 t;
        #pragma unroll
        for (int e = 0; e < 8; ++e) t[e] = (short)f2bf(src[e] * QSCALE);
        aq[h] = t;
    }

    const int qrow = qb * QB + wq0 + li;          // this lane's pass-2 q row
    const unsigned long long* mrow = mb + (size_t)qrow * MWORDS;

    // ================= pass 1: wave-pair tile-split row sums =================
    const int half = wave >> 2;          // 0: tiles 0..31, 1: tiles 32..63
    const int w4   = wave & 3;
    const int kt0  = half * NTH;

    // pass-1 Q fragments: rows w4*32 + u*16 + li (2 sets per wave)
    short8 aq1[2][2];
    #pragma unroll
    for (int u = 0; u < 2; ++u)
        #pragma unroll
        for (int h = 0; h < 2; ++h) {
            const float* src = Qg + (w4 * 32 + u * 16 + li) * HD + h * 32 + g * 8;
            short8 t;
            #pragma unroll
            for (int e = 0; e < 8; ++e) t[e] = (short)f2bf(src[e] * QSCALE);
            aq1[u][h] = t;
        }
    const unsigned long long* m1[2] = {
        mb + (size_t)(qb * QB + w4 * 32 + li) * MWORDS,
        mb + (size_t)(qb * QB + w4 * 32 + 16 + li) * MWORDS
    };
    char* buf0 = half ? LdsV[0] : LdsK[0];
    char* buf1 = half ? LdsV[1] : LdsK[1];
    char* buf2 = half ? LdsV[2] : LdsK[2];
    char* bufs[3] = { buf0, buf1, buf2 };

    STAGE_P1(0, buf0);
    STAGE_P1(1, buf1);
    asm volatile("s_waitcnt vmcnt(2)" ::: "memory");   // tile kt0 landed; kt0+1 in flight
    __builtin_amdgcn_s_barrier();
    asm volatile("" ::: "memory");

    float lsum[2] = {0.f, 0.f};
    for (int t = 0; t < NTH; ++t) {
        if (t + 2 < NTH) STAGE_P1(t + 2, bufs[(t + 2) % 3]);
        const unsigned long long mw0 = m1[0][kt0 + t];
        const unsigned long long mw1 = m1[1][kt0 + t];

        const char* Kb = bufs[t % 3] + lane * 16;
        short8 bk[4][2];
        #pragma unroll
        for (int tt = 0; tt < 4; ++tt)
            #pragma unroll
            for (int h = 0; h < 2; ++h)
                bk[tt][h] = *(const short8*)(Kb + (tt * 2 + h) * 1024);

        #pragma unroll
        for (int u = 0; u < 2; ++u) {
            const unsigned long long mw = (u == 0) ? mw0 : mw1;
            float4v accs[4];
            #pragma unroll
            for (int tt = 0; tt < 4; ++tt) accs[tt] = (float4v){0.f, 0.f, 0.f, 0.f};
            __builtin_amdgcn_s_setprio(1);
            #pragma unroll
            for (int tt = 0; tt < 4; ++tt) {
                accs[tt] = __builtin_amdgcn_mfma_f32_16x16x32_bf16(bk[tt][0], aq1[u][0], accs[tt], 0, 0, 0);
                accs[tt] = __builtin_amdgcn_mfma_f32_16x16x32_bf16(bk[tt][1], aq1[u][1], accs[tt], 0, 0, 0);
            }
            __builtin_amdgcn_s_setprio(0);
            const uint32_t mlo = (uint32_t)mw >> (g * 8);
            const uint32_t mhi = (uint32_t)(mw >> 32) >> (g * 8);
            const uint32_t nib[4] = { mlo & 0xFu, (mlo >> 4) & 0xFu, mhi & 0xFu, (mhi >> 4) & 0xFu };
            float ls = 0.f;
            #pragma unroll
            for (int tt = 0; tt < 4; ++tt)
                #pragma unroll
                for (int r = 0; r < 4; ++r) {
                    const float e = exp2_hw(accs[tt][r]);
                    ls += ((nib[tt] >> r) & 1u) ? e : 0.f;
                }
            lsum[u] += ls;
        }

        if (t < NTH - 2) {
            asm volatile("s_waitcnt vmcnt(2)" ::: "memory");   // leave stage(t+2)
            __builtin_amdgcn_s_barrier();
            asm volatile("" ::: "memory");
        } else if (t == NTH - 2) {
            asm volatile("s_waitcnt vmcnt(0)" ::: "memory");
            __builtin_amdgcn_s_barrier();
            asm volatile("" ::: "memory");
        }
    }

    // merge halves via LDS (LdsK[3] unused in pass 1)
    float* lsumLds = (float*)LdsK[3];
    #pragma unroll
    for (int u = 0; u < 2; ++u) {
        float s = lsum[u];
        s += __shfl_xor(s, 16);
        s += __shfl_xor(s, 32);
        if (g == 0) lsumLds[half * 128 + w4 * 32 + u * 16 + li] = s;
    }
    __syncthreads();
    const float linv2 = -log2_hw(lsumLds[wq0 + li] + lsumLds[128 + wq0 + li]);

    // ================= pass 2: phase-staggered QK/FIN slots (R18) =================
    float* attnT = attng + (size_t)bh * SEQ * SEQ + (size_t)qrow * SEQ + g * 8;
    float4v acco[4];
    #pragma unroll
    for (int dt = 0; dt < 4; ++dt) acco[dt] = (float4v){0.f, 0.f, 0.f, 0.f};

    const int odd = wave & 1;
    const int ew  = wave >> 1;    // even-wave staging index

    unsigned long long mwreg = mrow[0];
    if (!odd) {
        STAGE2_K(0); STAGE2_V(0);
        STAGE2_K(1); STAGE2_V(1);
        asm volatile("s_waitcnt vmcnt(0)" ::: "memory");
    }
    __builtin_amdgcn_s_barrier();      // also protects lsumLds reads vs LdsK[3] staging
    asm volatile("" ::: "memory");

    float4v accs[4];
    for (int slot = 0; slot < 2 * NT + 1; ++slot) {
        const int shalf = slot & 1;
        int t_qk = -1, t_fin = -1;
        if (!odd) {
            if (!shalf) { const int t = slot >> 1; if (t < NT) t_qk = t; }
            else        t_fin = slot >> 1;
        } else {
            if (shalf)  t_qk = slot >> 1;
            else if (slot > 0) t_fin = (slot >> 1) - 1;
        }

        if (t_qk >= 0) {   // QK phase: stage (evens) + ds_read K + MFMA -> accs
            if (!odd && t_qk + 2 < NT) { STAGE2_K(t_qk + 2); STAGE2_V(t_qk + 2); }
            const char* Kb = LdsK[t_qk & 3] + lane * 16;
            short8 bk[4][2];
            #pragma unroll
            for (int t = 0; t < 4; ++t)
                #pragma unroll
                for (int h = 0; h < 2; ++h)
                    bk[t][h] = *(const short8*)(Kb + (t * 2 + h) * 1024);
            #pragma unroll
            for (int t = 0; t < 4; ++t) accs[t] = (float4v){0.f, 0.f, 0.f, 0.f};
            __builtin_amdgcn_s_setprio(1);
            #pragma unroll
            for (int t = 0; t < 4; ++t) {
                accs[t] = __builtin_amdgcn_mfma_f32_16x16x32_bf16(bk[t][0], aq[0], accs[t], 0, 0, 0);
                accs[t] = __builtin_amdgcn_mfma_f32_16x16x32_bf16(bk[t][1], aq[1], accs[t], 0, 0, 0);
            }
            __builtin_amdgcn_s_setprio(0);
        }

        if (t_fin >= 0) {  // FIN phase: ds_read V + softmax + stores + PV
            const char* Vb = LdsV[t_fin & 3] + lane * 16;
            short8 vb[4][2];
            #pragma unroll
            for (int t = 0; t < 4; ++t)
                #pragma unroll
                for (int h = 0; h < 2; ++h)
                    vb[t][h] = *(const short8*)(Vb + (t * 2 + h) * 1024);

            const uint32_t mlo = (uint32_t)mwreg >> (g * 8);
            const uint32_t mhi = (uint32_t)(mwreg >> 32) >> (g * 8);
            const uint32_t nib[4] = { mlo & 0xFu, (mlo >> 4) & 0xFu, mhi & 0xFu, (mhi >> 4) & 0xFu };
            float4v pv[4];
            #pragma unroll
            for (int t = 0; t < 4; ++t)
                #pragma unroll
                for (int r = 0; r < 4; ++r) {
                    const float e = exp2_hw(accs[t][r] + linv2);
                    pv[t][r] = ((nib[t] >> r) & 1u) ? e : 0.f;
                }

            float* ap = attnT + t_fin * KT;
            *(float4v*)(ap)      = pv[0];
            *(float4v*)(ap + 4)  = pv[1];
            *(float4v*)(ap + 32) = pv[2];
            *(float4v*)(ap + 36) = pv[3];

            if (t_fin + 1 < NT) mwreg = mrow[t_fin + 1];

            uint32_t pk[4][2];
            #pragma unroll
            for (int t = 0; t < 4; ++t) {
                pk[t][0] = cvt_pk_bf16(pv[t][0], pv[t][1]);
                pk[t][1] = cvt_pk_bf16(pv[t][2], pv[t][3]);
            }
            union { uint32_t u[4]; short8 s; } pa0, pa1;
            pa0.u[0] = pk[0][0]; pa0.u[1] = pk[0][1]; pa0.u[2] = pk[1][0]; pa0.u[3] = pk[1][1];
            pa1.u[0] = pk[2][0]; pa1.u[1] = pk[2][1]; pa1.u[2] = pk[3][0]; pa1.u[3] = pk[3][1];

            __builtin_amdgcn_s_setprio(1);
            #pragma unroll
            for (int dt = 0; dt < 4; ++dt) {
                acco[dt] = __builtin_amdgcn_mfma_f32_16x16x32_bf16(vb[dt][0], pa0.s, acco[dt], 0, 0, 0);
                acco[dt] = __builtin_amdgcn_mfma_f32_16x16x32_bf16(vb[dt][1], pa1.s, acco[dt], 0, 0, 0);
            }
            __builtin_amdgcn_s_setprio(0);
        }

        if (slot < 2 * NT) {
            if (t_qk >= 0 || t_fin >= 0)
                asm volatile("s_waitcnt vmcnt(5)" ::: "memory");
            __builtin_amdgcn_s_barrier();
            asm volatile("" ::: "memory");
        }
    }

    // ---- write output: lane (g,li) owns out[qrow][dt*16+g*4 .. +3] ----
    float* outW = outg + qkvBase + (size_t)qrow * HD + g * 4;
    #pragma unroll
    for (int dt = 0; dt < 4; ++dt) {
        *(float4v*)(outW + dt * 16) = acco[dt];
    }
}

extern "C" void kernel_launch(void* const* d_in, const int* in_sizes, int n_in,
                              void* d_out, int out_size, void* d_ws, size_t ws_size,
                              hipStream_t stream) {
    (void)in_sizes; (void)n_in; (void)out_size; (void)ws_size;
    const float* q = (const float*)d_in[0];
    const float* k = (const float*)d_in[1];
    const float* v = (const float*)d_in[2];
    const int* mask = (const int*)d_in[3];

    float* outp  = (float*)d_out;
    float* attnp = outp + (size_t)2 * 8 * SEQ * HD;

    // ws layout: [0,2MB) mask bits | [2MB,10MB) K tiles | [10MB,18MB) V tiles
    char* ws = (char*)d_ws;
    unsigned long long* mb = (unsigned long long*)ws;
    char* ktiles = ws + (size_t)2 * 1024 * 1024;
    char* vtiles = ws + (size_t)10 * 1024 * 1024;

    pack_mask_kernel<<<SEQ, 256, 0, stream>>>(mask, mb);
    prep_kv_kernel<<<HEADS * NT, 256, 0, stream>>>(k, v, ktiles, vtiles);
    attn_kernel<<<HEADS * (SEQ / QB), 512, 0, stream>>>(q, mb, ktiles, vtiles, outp, attnp);
}